// Round 1
// baseline (288.046 us; speedup 1.0000x reference)
//
#include <hip/hip_runtime.h>

// PointPillarScatter: out[b][c][y][x] = feat[p][c] where coords[p]=(x,y,b), else 0.
//
// v2: channel-major gather with a SEQUENTIAL write stream.
// The previous cell-per-thread gather wrote 64 x 256B chunks per wave at
// stride plane (857 KB) -> thousands of interleaved scattered 256B streams ->
// poor DRAM row locality (~2.4 TB/s). Here blockIdx.y = c and blockIdx.x
// sweeps cells, so consecutive blocks write consecutive float4s exactly like
// fillBufferAligned (6.7 TB/s on this buffer). map is re-read once per
// channel but stays L2-resident; feat gathers are scattered dwords served by
// L2/L3 (feat is only 10 MB).

#define C_CH 64

__global__ void build_map_kernel(const int* __restrict__ coords, int n_pillars,
                                 const int* __restrict__ nx_p,
                                 const int* __restrict__ ny_p,
                                 int* __restrict__ map) {
    int p = blockIdx.x * blockDim.x + threadIdx.x;
    if (p >= n_pillars) return;
    const int nx = nx_p[0];
    const int ny = ny_p[0];
    const int x = coords[3 * p + 0];
    const int y = coords[3 * p + 1];
    const int b = coords[3 * p + 2];
    const long long m = (long long)b * (long long)(nx * ny) + (long long)y * nx + x;
    map[m] = p;
}

// One thread per output float4 of a single channel plane.
// grid = (ceil(n_map/4/256), C_CH); block = 256.
// Writes are globally sequential (consecutive blocks -> consecutive 16 KB).
__global__ void gather_c4_kernel(const float* __restrict__ feat,
                                 const int* __restrict__ map,
                                 const int* __restrict__ nx_p,
                                 const int* __restrict__ ny_p,
                                 float* __restrict__ out, int n_map) {
    const int c = blockIdx.y;
    const int cell = (blockIdx.x * blockDim.x + threadIdx.x) * 4;
    if (cell >= n_map) return;
    const int plane = nx_p[0] * ny_p[0];   // uniform

    if ((plane & 3) == 0) {
        // Fast path: every quad is 16B-aligned in both map and out, and never
        // straddles a batch boundary (plane % 4 == 0 => n_map % 4 == 0).
        const int4 m = *reinterpret_cast<const int4*>(map + cell);
        const unsigned b = (unsigned)cell / (unsigned)plane;   // uniform divisor
        const int local = cell - (int)b * plane;

        float4 v;
        v.x = (m.x >= 0) ? feat[(size_t)m.x * C_CH + c] : 0.0f;
        v.y = (m.y >= 0) ? feat[(size_t)m.y * C_CH + c] : 0.0f;
        v.z = (m.z >= 0) ? feat[(size_t)m.z * C_CH + c] : 0.0f;
        v.w = (m.w >= 0) ? feat[(size_t)m.w * C_CH + c] : 0.0f;

        *reinterpret_cast<float4*>(
            out + ((size_t)b * C_CH + c) * (size_t)plane + local) = v;
    } else {
        // Generic path (plane not divisible by 4): scalar stores.
#pragma unroll
        for (int i = 0; i < 4; ++i) {
            const int cl = cell + i;
            if (cl >= n_map) break;
            const int b = cl / plane;
            const int local = cl - b * plane;
            const int p = map[cl];
            out[((size_t)b * C_CH + c) * (size_t)plane + local] =
                (p >= 0) ? feat[(size_t)p * C_CH + c] : 0.0f;
        }
    }
}

// Fallback: direct scatter after zeroing the output (used only if ws is too
// small for the map or C != 64).
__global__ void direct_scatter_kernel(const float* __restrict__ feat,
                                      const int* __restrict__ coords,
                                      int n_pillars, int C,
                                      const int* __restrict__ nx_p,
                                      const int* __restrict__ ny_p,
                                      float* __restrict__ out) {
    const long long t = (long long)blockIdx.x * blockDim.x + threadIdx.x;
    if (t >= (long long)n_pillars * C) return;
    const int p = (int)(t / C);
    const int c = (int)(t - (long long)p * C);
    const int nx = nx_p[0];
    const int ny = ny_p[0];
    const int x = coords[3 * p + 0];
    const int y = coords[3 * p + 1];
    const int b = coords[3 * p + 2];
    const int plane = nx * ny;
    const size_t o = ((size_t)b * C + c) * (size_t)plane + (size_t)y * nx + x;
    out[o] = feat[(size_t)p * C + c];
}

extern "C" void kernel_launch(void* const* d_in, const int* in_sizes, int n_in,
                              void* d_out, int out_size, void* d_ws, size_t ws_size,
                              hipStream_t stream) {
    const float* feat   = (const float*)d_in[0];
    const int*   coords = (const int*)d_in[1];
    // d_in[2] = batch_size (device scalar, unused on host), d_in[3] = nx,
    // d_in[4] = ny — device-resident scalars, read inside the kernels.
    const int* nx_p = (const int*)d_in[3];
    const int* ny_p = (const int*)d_in[4];
    float* out = (float*)d_out;

    const int n_pillars = in_sizes[1] / 3;
    const int C = in_sizes[0] / n_pillars;
    const int n_map = out_size / C;                 // B * NY * NX
    const size_t map_bytes = (size_t)n_map * sizeof(int);

    if (C == C_CH && ws_size >= map_bytes) {
        int* map = (int*)d_ws;
        // 0xFF bytes -> every map entry == -1
        hipMemsetAsync(map, 0xFF, map_bytes, stream);
        build_map_kernel<<<(n_pillars + 255) / 256, 256, 0, stream>>>(
            coords, n_pillars, nx_p, ny_p, map);

        const int n_quads = (n_map + 3) / 4;
        dim3 grid((n_quads + 255) / 256, C_CH, 1);
        gather_c4_kernel<<<grid, 256, 0, stream>>>(
            feat, map, nx_p, ny_p, out, n_map);
    } else {
        hipMemsetAsync(out, 0, (size_t)out_size * sizeof(float), stream);
        const long long total = (long long)n_pillars * C;
        direct_scatter_kernel<<<(unsigned)((total + 255) / 256), 256, 0, stream>>>(
            feat, coords, n_pillars, C, nx_p, ny_p, out);
    }
}

// Round 3
// 254.839 us; speedup vs baseline: 1.1303x; 1.1303x over previous
//
#include <hip/hip_runtime.h>

// PointPillarScatter: out[b][c][y][x] = feat[p][c] where coords[p]=(x,y,b), else 0.
//
// v3b: read-once / write-once with LDS transpose. (v3 + compile fix: the
// nontemporal builtin needs a native clang vector type, not HIP float4.)
//  - v1 (cell-per-thread): read-once but writes were 256B chunks interleaved
//    across 64 planes -> DRAM row thrash, ~2.4 TB/s effective store BW.
//  - v2 (channel-major): sequential writes but map re-read 64x and the write
//    stream evicted L2, so reads ballooned to ~300 MB -> regression.
//  - v3: block owns 1024 cells; map read once into regs; 4 passes over
//    channel-groups of 16 (one 64B feat line per pillar per pass -> feat read
//    exactly once); LDS transpose; write-out streams 4KB per plane as
//    back-to-back 1KB wave stores (nontemporal, so L2 keeps map/feat).

#define C_CH 64
#define CELLS 1024
#define CH_PASS 16
#define NPASS (C_CH / CH_PASS)
#define BLOCK 256

typedef float fvec4 __attribute__((ext_vector_type(4)));

__global__ void build_map_kernel(const int* __restrict__ coords, int n_pillars,
                                 const int* __restrict__ nx_p,
                                 const int* __restrict__ ny_p,
                                 int* __restrict__ map) {
    int p = blockIdx.x * blockDim.x + threadIdx.x;
    if (p >= n_pillars) return;
    const int nx = nx_p[0];
    const int ny = ny_p[0];
    const int x = coords[3 * p + 0];
    const int y = coords[3 * p + 1];
    const int b = coords[3 * p + 2];
    const long long m = (long long)b * (long long)(nx * ny) + (long long)y * nx + x;
    map[m] = p;
}

__global__ __launch_bounds__(BLOCK, 2) void gather_tile_kernel(
    const float* __restrict__ feat, const int* __restrict__ map,
    const int* __restrict__ nx_p, const int* __restrict__ ny_p,
    float* __restrict__ out, int n_map) {
    __shared__ float lds[CH_PASS][CELLS];   // 64 KB -> 2 blocks/CU

    const int t = threadIdx.x;
    const int w = t >> 6;          // wave id 0..3
    const int l = t & 63;          // lane
    const int cl_base = blockIdx.x * CELLS;
    const int plane = nx_p[0] * ny_p[0];    // uniform

    // Each thread owns cells cl_base + t + 256*j (strided => bank-free LDS,
    // coalesced map loads). Map read ONCE, kept in registers across passes.
    int pidx[4];
#pragma unroll
    for (int j = 0; j < 4; ++j) {
        const int cl = cl_base + t + BLOCK * j;
        pidx[j] = (cl < n_map) ? map[cl] : -1;
    }

    // Fast path: whole tile inside one batch plane, 16B-alignment guaranteed.
    const int b0 = cl_base / plane;
    const int local0 = cl_base - b0 * plane;
    const bool fast = ((plane & 3) == 0) && (cl_base + CELLS <= n_map) &&
                      ((cl_base + CELLS - 1) / plane == b0);

    for (int cg = 0; cg < NPASS; ++cg) {
        // ---- gather phase: one 64B feat line per pillar cell -> LDS ----
#pragma unroll
        for (int j = 0; j < 4; ++j) {
            const int pos = t + BLOCK * j;
            const int p = pidx[j];
            float vals[CH_PASS];
            if (p >= 0) {
                const float4* __restrict__ src =
                    (const float4*)(feat + (size_t)p * C_CH + cg * CH_PASS);
#pragma unroll
                for (int q = 0; q < CH_PASS / 4; ++q) {
                    const float4 v = src[q];
                    vals[4 * q + 0] = v.x;
                    vals[4 * q + 1] = v.y;
                    vals[4 * q + 2] = v.z;
                    vals[4 * q + 3] = v.w;
                }
            } else {
#pragma unroll
                for (int q = 0; q < CH_PASS; ++q) vals[q] = 0.0f;
            }
#pragma unroll
            for (int q = 0; q < CH_PASS; ++q) lds[q][pos] = vals[q];
        }
        __syncthreads();

        // ---- write-out phase: wave w streams planes 4w..4w+3, 4KB each as
        //      4 back-to-back 1KB wave stores (sequential bursts) ----
#pragma unroll
        for (int pl = 0; pl < 4; ++pl) {
            const int cc = 4 * w + pl;
            const int c = cg * CH_PASS + cc;
            if (fast) {
                fvec4* __restrict__ dst =
                    (fvec4*)(out + ((size_t)(b0 * C_CH + c)) * (size_t)plane +
                             local0);
                const fvec4* __restrict__ src = (const fvec4*)&lds[cc][0];
#pragma unroll
                for (int k = 0; k < CELLS / 256; ++k) {
                    __builtin_nontemporal_store(src[64 * k + l], &dst[64 * k + l]);
                }
            } else {
                // Rare: batch-boundary or tail tile -> scalar with guards.
                for (int k = 0; k < CELLS / 256; ++k) {
                    for (int e = 0; e < 4; ++e) {
                        const int off = 256 * k + 4 * l + e;
                        const int cell = cl_base + off;
                        if (cell < n_map) {
                            const int b = cell / plane;
                            const int local = cell - b * plane;
                            out[((size_t)(b * C_CH + c)) * (size_t)plane + local] =
                                lds[cc][off];
                        }
                    }
                }
            }
        }
        __syncthreads();   // protect lds before next pass overwrites it
    }
}

// Fallback: direct scatter after zeroing the output (used only if ws is too
// small for the map or C != 64).
__global__ void direct_scatter_kernel(const float* __restrict__ feat,
                                      const int* __restrict__ coords,
                                      int n_pillars, int C,
                                      const int* __restrict__ nx_p,
                                      const int* __restrict__ ny_p,
                                      float* __restrict__ out) {
    const long long t = (long long)blockIdx.x * blockDim.x + threadIdx.x;
    if (t >= (long long)n_pillars * C) return;
    const int p = (int)(t / C);
    const int c = (int)(t - (long long)p * C);
    const int nx = nx_p[0];
    const int ny = ny_p[0];
    const int x = coords[3 * p + 0];
    const int y = coords[3 * p + 1];
    const int b = coords[3 * p + 2];
    const int plane = nx * ny;
    const size_t o = ((size_t)b * C + c) * (size_t)plane + (size_t)y * nx + x;
    out[o] = feat[(size_t)p * C + c];
}

extern "C" void kernel_launch(void* const* d_in, const int* in_sizes, int n_in,
                              void* d_out, int out_size, void* d_ws, size_t ws_size,
                              hipStream_t stream) {
    const float* feat   = (const float*)d_in[0];
    const int*   coords = (const int*)d_in[1];
    // d_in[2] = batch_size (device scalar, unused on host), d_in[3] = nx,
    // d_in[4] = ny — device-resident scalars, read inside the kernels.
    const int* nx_p = (const int*)d_in[3];
    const int* ny_p = (const int*)d_in[4];
    float* out = (float*)d_out;

    const int n_pillars = in_sizes[1] / 3;
    const int C = in_sizes[0] / n_pillars;
    const int n_map = out_size / C;                 // B * NY * NX
    const size_t map_bytes = (size_t)n_map * sizeof(int);

    if (C == C_CH && ws_size >= map_bytes) {
        int* map = (int*)d_ws;
        // 0xFF bytes -> every map entry == -1
        (void)hipMemsetAsync(map, 0xFF, map_bytes, stream);
        build_map_kernel<<<(n_pillars + 255) / 256, 256, 0, stream>>>(
            coords, n_pillars, nx_p, ny_p, map);

        const int n_tiles = (n_map + CELLS - 1) / CELLS;
        gather_tile_kernel<<<n_tiles, BLOCK, 0, stream>>>(
            feat, map, nx_p, ny_p, out, n_map);
    } else {
        (void)hipMemsetAsync(out, 0, (size_t)out_size * sizeof(float), stream);
        const long long total = (long long)n_pillars * C;
        direct_scatter_kernel<<<(unsigned)((total + 255) / 256), 256, 0, stream>>>(
            feat, coords, n_pillars, C, nx_p, ny_p, out);
    }
}

// Round 5
// 252.688 us; speedup vs baseline: 1.1399x; 1.0085x over previous
//
#include <hip/hip_runtime.h>

// PointPillarScatter: out[b][c][y][x] = feat[p][c] where coords[p]=(x,y,b), else 0.
//
// v4: LDS-transpose gather, occupancy- and instruction-fixed.
// Ladder so far (graph-time after ~165us fixed harness floor):
//  - v1 cell-per-thread: ~67us. 256B chunks interleaved across 64 planes.
//  - v2 channel-major:  ~122us. map re-read 64x from HBM, scattered feat.
//  - v3b 64KB LDS:      ~84us. Right bursts (4KB/plane) but 2 blocks/CU and
//    256 unconditional scalar ds_writes/thread (95.3% of cells are EMPTY).
//  - v4: 32KB LDS -> 4-5 blocks/CU; zero phase = 8 b128 LDS writes; sparse
//    scatter only for occupied cells; same 4KB sequential bursts per plane.

#define C_CH 64
#define CELLS 1024
#define CH_PASS 8
#define NPASS (C_CH / CH_PASS)
#define BLOCK 256
#define J_PER (CELLS / BLOCK)

typedef float fvec4 __attribute__((ext_vector_type(4)));

__global__ void build_map_kernel(const int* __restrict__ coords, int n_pillars,
                                 const int* __restrict__ nx_p,
                                 const int* __restrict__ ny_p,
                                 int* __restrict__ map) {
    int p = blockIdx.x * blockDim.x + threadIdx.x;
    if (p >= n_pillars) return;
    const int nx = nx_p[0];
    const int ny = ny_p[0];
    const int x = coords[3 * p + 0];
    const int y = coords[3 * p + 1];
    const int b = coords[3 * p + 2];
    const long long m = (long long)b * (long long)(nx * ny) + (long long)y * nx + x;
    map[m] = p;
}

__global__ __launch_bounds__(BLOCK, 4) void gather_tile8_kernel(
    const float* __restrict__ feat, const int* __restrict__ map,
    const int* __restrict__ nx_p, const int* __restrict__ ny_p,
    float* __restrict__ out, int n_map) {
    __shared__ float lds[CH_PASS][CELLS];   // 32 KB -> 4-5 blocks/CU

    const int t = threadIdx.x;
    const int w = t >> 6;          // wave id 0..3
    const int l = t & 63;          // lane
    const int cl_base = blockIdx.x * CELLS;
    const int plane = nx_p[0] * ny_p[0];    // uniform

    // Map read once, kept in registers across all passes.
    int pidx[J_PER];
#pragma unroll
    for (int j = 0; j < J_PER; ++j) {
        const int cl = cl_base + t + BLOCK * j;
        pidx[j] = (cl < n_map) ? map[cl] : -1;
    }

    const int b0 = cl_base / plane;
    const int local0 = cl_base - b0 * plane;
    const bool fast = ((plane & 3) == 0) && (cl_base + CELLS <= n_map) &&
                      ((cl_base + CELLS - 1) / plane == b0);

    for (int cg = 0; cg < NPASS; ++cg) {
        // ---- Phase A: zero the whole 32KB tile with wave-contiguous b128 ----
        {
            fvec4* __restrict__ Lz = (fvec4*)&lds[0][0];
#pragma unroll
            for (int i = 0; i < (CH_PASS * CELLS / 4) / BLOCK; ++i) {  // 8
                Lz[t + BLOCK * i] = (fvec4)0.0f;
            }
        }
        __syncthreads();

        // ---- Phase B: sparse scatter — only ~4.7% of cells are occupied ----
#pragma unroll
        for (int j = 0; j < J_PER; ++j) {
            const int p = pidx[j];
            if (p >= 0) {
                const int pos = t + BLOCK * j;
                const float4* __restrict__ src =
                    (const float4*)(feat + (size_t)p * C_CH + cg * CH_PASS);
                const float4 v0 = src[0];
                const float4 v1 = src[1];
                lds[0][pos] = v0.x; lds[1][pos] = v0.y;
                lds[2][pos] = v0.z; lds[3][pos] = v0.w;
                lds[4][pos] = v1.x; lds[5][pos] = v1.y;
                lds[6][pos] = v1.z; lds[7][pos] = v1.w;
            }
        }
        __syncthreads();

        // ---- Phase C: write-out, wave w streams planes 2w, 2w+1 as 4KB of
        //      back-to-back 1KB wave stores (sequential bursts) ----
#pragma unroll
        for (int pl = 0; pl < 2; ++pl) {
            const int cc = 2 * w + pl;
            const int c = cg * CH_PASS + cc;
            if (fast) {
                fvec4* __restrict__ dst =
                    (fvec4*)(out + ((size_t)(b0 * C_CH + c)) * (size_t)plane +
                             local0);
                const fvec4* __restrict__ srcl = (const fvec4*)&lds[cc][0];
#pragma unroll
                for (int k = 0; k < CELLS / 256; ++k) {   // 4
                    __builtin_nontemporal_store(srcl[64 * k + l], &dst[64 * k + l]);
                }
            } else {
                // Rare: batch-boundary or tail tile -> scalar with guards.
                for (int k = 0; k < CELLS / 256; ++k) {
                    for (int e = 0; e < 4; ++e) {
                        const int off = 256 * k + 4 * l + e;
                        const int cell = cl_base + off;
                        if (cell < n_map) {
                            const int b = cell / plane;
                            const int local = cell - b * plane;
                            out[((size_t)(b * C_CH + c)) * (size_t)plane + local] =
                                lds[cc][off];
                        }
                    }
                }
            }
        }
        __syncthreads();   // protect lds before next pass's zero phase
    }
}

// Fallback: direct scatter after zeroing the output (used only if ws is too
// small for the map or C != 64).
__global__ void direct_scatter_kernel(const float* __restrict__ feat,
                                      const int* __restrict__ coords,
                                      int n_pillars, int C,
                                      const int* __restrict__ nx_p,
                                      const int* __restrict__ ny_p,
                                      float* __restrict__ out) {
    const long long t = (long long)blockIdx.x * blockDim.x + threadIdx.x;
    if (t >= (long long)n_pillars * C) return;
    const int p = (int)(t / C);
    const int c = (int)(t - (long long)p * C);
    const int nx = nx_p[0];
    const int ny = ny_p[0];
    const int x = coords[3 * p + 0];
    const int y = coords[3 * p + 1];
    const int b = coords[3 * p + 2];
    const int plane = nx * ny;
    const size_t o = ((size_t)b * C + c) * (size_t)plane + (size_t)y * nx + x;
    out[o] = feat[(size_t)p * C + c];
}

extern "C" void kernel_launch(void* const* d_in, const int* in_sizes, int n_in,
                              void* d_out, int out_size, void* d_ws, size_t ws_size,
                              hipStream_t stream) {
    const float* feat   = (const float*)d_in[0];
    const int*   coords = (const int*)d_in[1];
    // d_in[2] = batch_size (device scalar, unused on host), d_in[3] = nx,
    // d_in[4] = ny — device-resident scalars, read inside the kernels.
    const int* nx_p = (const int*)d_in[3];
    const int* ny_p = (const int*)d_in[4];
    float* out = (float*)d_out;

    const int n_pillars = in_sizes[1] / 3;
    const int C = in_sizes[0] / n_pillars;
    const int n_map = out_size / C;                 // B * NY * NX
    const size_t map_bytes = (size_t)n_map * sizeof(int);

    if (C == C_CH && ws_size >= map_bytes) {
        int* map = (int*)d_ws;
        // 0xFF bytes -> every map entry == -1
        (void)hipMemsetAsync(map, 0xFF, map_bytes, stream);
        build_map_kernel<<<(n_pillars + 255) / 256, 256, 0, stream>>>(
            coords, n_pillars, nx_p, ny_p, map);

        const int n_tiles = (n_map + CELLS - 1) / CELLS;
        gather_tile8_kernel<<<n_tiles, BLOCK, 0, stream>>>(
            feat, map, nx_p, ny_p, out, n_map);
    } else {
        (void)hipMemsetAsync(out, 0, (size_t)out_size * sizeof(float), stream);
        const long long total = (long long)n_pillars * C;
        direct_scatter_kernel<<<(unsigned)((total + 255) / 256), 256, 0, stream>>>(
            feat, coords, n_pillars, C, nx_p, ny_p, out);
    }
}

// Round 6
// 252.462 us; speedup vs baseline: 1.1409x; 1.0009x over previous
//
#include <hip/hip_runtime.h>

// PointPillarScatter: out[b][c][y][x] = feat[p][c] where coords[p]=(x,y,b), else 0.
//
// v5: zero-fill + sparse scatter. Pivot after v3/v4 refuted the write-burst
// theory: every design where all 219.5 MB of output flows through thread
// registers is stuck at 2.0-2.8 TB/s effective, while the runtime fill
// writes the SAME buffer at 6.5-6.7 TB/s (measured every round). The output
// is 95.3% zeros: only 40000 pillars x 64 ch x 4B = 10.2 MB is real data.
// So: hipMemsetAsync writes the zeros at fill speed (~33 us), then a single
// scatter kernel writes the 10 MB payload:
//   - thread per (p,c): lane = channel -> feat reads fully coalesced
//     (256 B per wave), one scattered 4 B store per thread.
//   - 2.56 M store transactions / 256 CUs ~ 10K cycles/CU ~ 5-15 us.
// No map, no workspace, no build step, no LDS, no races (cells unique).

__global__ void scatter_kernel(const float* __restrict__ feat,
                               const int* __restrict__ coords,
                               int n_pillars, int C,
                               const int* __restrict__ nx_p,
                               const int* __restrict__ ny_p,
                               float* __restrict__ out) {
    const long long t = (long long)blockIdx.x * blockDim.x + threadIdx.x;
    if (t >= (long long)n_pillars * C) return;

    int p, c;
    if (C == 64) {          // fast path: shifts, no integer divide
        p = (int)(t >> 6);
        c = (int)(t & 63);
    } else {
        p = (int)(t / C);
        c = (int)(t - (long long)p * C);
    }

    const int nx = nx_p[0];
    const int ny = ny_p[0];
    const int plane = nx * ny;

    const int x = coords[3 * p + 0];
    const int y = coords[3 * p + 1];
    const int b = coords[3 * p + 2];

    // feat read: t = p*C + c, consecutive lanes -> consecutive floats.
    const float v = feat[t];

    const size_t o = ((size_t)b * C + c) * (size_t)plane + (size_t)y * nx + x;
    out[o] = v;
}

extern "C" void kernel_launch(void* const* d_in, const int* in_sizes, int n_in,
                              void* d_out, int out_size, void* d_ws, size_t ws_size,
                              hipStream_t stream) {
    const float* feat   = (const float*)d_in[0];
    const int*   coords = (const int*)d_in[1];
    // d_in[2] = batch_size (device scalar, unused on host), d_in[3] = nx,
    // d_in[4] = ny — device-resident scalars, read inside the kernel.
    const int* nx_p = (const int*)d_in[3];
    const int* ny_p = (const int*)d_in[4];
    float* out = (float*)d_out;

    const int n_pillars = in_sizes[1] / 3;
    const int C = in_sizes[0] / n_pillars;

    // Phase 1: zeros at fill speed (~6.7 TB/s measured on this buffer).
    (void)hipMemsetAsync(out, 0, (size_t)out_size * sizeof(float), stream);

    // Phase 2: scatter the 4.7% occupied payload.
    const long long total = (long long)n_pillars * C;
    const unsigned nblocks = (unsigned)((total + 255) / 256);
    scatter_kernel<<<nblocks, 256, 0, stream>>>(
        feat, coords, n_pillars, C, nx_p, ny_p, out);
}

// Round 7
// 246.909 us; speedup vs baseline: 1.1666x; 1.0225x over previous
//
#include <hip/hip_runtime.h>

// PointPillarScatter: out[b][c][y][x] = feat[p][c] where coords[p]=(x,y,b), else 0.
//
// v6: v1's fused zero+gather structure (the best measured: each output line
// written exactly once with final contents, read-once map/feat), with two
// store-side deltas and nothing else:
//   1. thread owns 4 consecutive cells -> dwordx4 stores, 1KB contiguous per
//      wave-store-instruction (4x v1's 256B granule), 4x fewer store instrs.
//   2. nontemporal stores -> 219MB write stream bypasses L2 (map/feat stay
//      cached; writeback ordering can't scramble the stream).
// Ladder (graph-time after ~165us harness floor): v1 fused=68us(3.4TB/s),
// v2 chan-major=123(read explosion), v3b/v4 LDS=85-88(machinery),
// v5 memset+scatter=88(partial-line RMW). Store locality is the one lever
// left; the runtime fill proves 6.7TB/s needs locality, not occupancy.

#define C_CH 64

typedef float fvec4 __attribute__((ext_vector_type(4)));

__global__ void build_map_kernel(const int* __restrict__ coords, int n_pillars,
                                 const int* __restrict__ nx_p,
                                 const int* __restrict__ ny_p,
                                 int* __restrict__ map) {
    int p = blockIdx.x * blockDim.x + threadIdx.x;
    if (p >= n_pillars) return;
    const int nx = nx_p[0];
    const int ny = ny_p[0];
    const int x = coords[3 * p + 0];
    const int y = coords[3 * p + 1];
    const int b = coords[3 * p + 2];
    const long long m = (long long)b * (long long)(nx * ny) + (long long)y * nx + x;
    map[m] = p;
}

// Thread handles 4 consecutive cells, all 64 channels, in 4 channel-passes of
// 16. Stores are float4 (4 cells of one channel), nontemporal.
__global__ __launch_bounds__(256) void gather4_kernel(
    const float* __restrict__ feat, const int* __restrict__ map,
    const int* __restrict__ nx_p, const int* __restrict__ ny_p,
    float* __restrict__ out, int n_map) {
    const int t = blockIdx.x * blockDim.x + threadIdx.x;
    const int cell0 = t * 4;
    if (cell0 >= n_map) return;

    const int plane = nx_p[0] * ny_p[0];   // uniform
    const int b = cell0 / plane;
    const int local0 = cell0 - b * plane;

    if ((plane & 3) == 0) {
        // Fast path: 4 cells share one plane, 16B-aligned everywhere.
        const int4 m = *reinterpret_cast<const int4*>(map + cell0);
        const int pj[4] = {m.x, m.y, m.z, m.w};
        const size_t obase = (size_t)(b * C_CH) * (size_t)plane + local0;

#pragma unroll
        for (int cg = 0; cg < 4; ++cg) {
            float v[16][4];   // v[ch][cell] — all indices static after unroll
#pragma unroll
            for (int ch = 0; ch < 16; ++ch)
#pragma unroll
                for (int j = 0; j < 4; ++j) v[ch][j] = 0.0f;

#pragma unroll
            for (int j = 0; j < 4; ++j) {
                const int p = pj[j];
                if (p >= 0) {
                    const fvec4* __restrict__ src =
                        (const fvec4*)(feat + (size_t)p * C_CH + cg * 16);
#pragma unroll
                    for (int i = 0; i < 4; ++i) {
                        const fvec4 f = src[i];
                        v[4 * i + 0][j] = f.x;
                        v[4 * i + 1][j] = f.y;
                        v[4 * i + 2][j] = f.z;
                        v[4 * i + 3][j] = f.w;
                    }
                }
            }

#pragma unroll
            for (int ch = 0; ch < 16; ++ch) {
                const int c = cg * 16 + ch;
                fvec4 o;
                o.x = v[ch][0]; o.y = v[ch][1]; o.z = v[ch][2]; o.w = v[ch][3];
                __builtin_nontemporal_store(
                    o, (fvec4*)(out + obase + (size_t)c * (size_t)plane));
            }
        }
    } else {
        // Generic path: scalar per-cell with batch-boundary guards.
        for (int j = 0; j < 4; ++j) {
            const int cell = cell0 + j;
            if (cell >= n_map) break;
            const int bb = cell / plane;
            const int local = cell - bb * plane;
            const int p = map[cell];
#pragma unroll
            for (int c = 0; c < C_CH; ++c) {
                const float val = (p >= 0) ? feat[(size_t)p * C_CH + c] : 0.0f;
                out[((size_t)(bb * C_CH + c)) * (size_t)plane + local] = val;
            }
        }
    }
}

// Fallback: direct scatter after zeroing the output (used only if ws is too
// small for the map, C != 64, or n_map not divisible by 4).
__global__ void direct_scatter_kernel(const float* __restrict__ feat,
                                      const int* __restrict__ coords,
                                      int n_pillars, int C,
                                      const int* __restrict__ nx_p,
                                      const int* __restrict__ ny_p,
                                      float* __restrict__ out) {
    const long long t = (long long)blockIdx.x * blockDim.x + threadIdx.x;
    if (t >= (long long)n_pillars * C) return;
    const int p = (int)(t / C);
    const int c = (int)(t - (long long)p * C);
    const int nx = nx_p[0];
    const int ny = ny_p[0];
    const int x = coords[3 * p + 0];
    const int y = coords[3 * p + 1];
    const int b = coords[3 * p + 2];
    const int plane = nx * ny;
    const size_t o = ((size_t)b * C + c) * (size_t)plane + (size_t)y * nx + x;
    out[o] = feat[(size_t)p * C + c];
}

extern "C" void kernel_launch(void* const* d_in, const int* in_sizes, int n_in,
                              void* d_out, int out_size, void* d_ws, size_t ws_size,
                              hipStream_t stream) {
    const float* feat   = (const float*)d_in[0];
    const int*   coords = (const int*)d_in[1];
    // d_in[2] = batch_size (device scalar, unused on host), d_in[3] = nx,
    // d_in[4] = ny — device-resident scalars, read inside the kernels.
    const int* nx_p = (const int*)d_in[3];
    const int* ny_p = (const int*)d_in[4];
    float* out = (float*)d_out;

    const int n_pillars = in_sizes[1] / 3;
    const int C = in_sizes[0] / n_pillars;
    const int n_map = out_size / C;                 // B * NY * NX
    const size_t map_bytes = (size_t)n_map * sizeof(int);

    if (C == C_CH && ws_size >= map_bytes && (n_map & 3) == 0) {
        int* map = (int*)d_ws;
        // 0xFF bytes -> every map entry == -1
        (void)hipMemsetAsync(map, 0xFF, map_bytes, stream);
        build_map_kernel<<<(n_pillars + 255) / 256, 256, 0, stream>>>(
            coords, n_pillars, nx_p, ny_p, map);

        const int n_threads = n_map / 4;
        gather4_kernel<<<(n_threads + 255) / 256, 256, 0, stream>>>(
            feat, map, nx_p, ny_p, out, n_map);
    } else {
        (void)hipMemsetAsync(out, 0, (size_t)out_size * sizeof(float), stream);
        const long long total = (long long)n_pillars * C;
        direct_scatter_kernel<<<(unsigned)((total + 255) / 256), 256, 0, stream>>>(
            feat, coords, n_pillars, C, nx_p, ny_p, out);
    }
}

// Round 8
// 236.744 us; speedup vs baseline: 1.2167x; 1.0429x over previous
//
#include <hip/hip_runtime.h>

// PointPillarScatter: out[b][c][y][x] = feat[p][c] where coords[p]=(x,y,b), else 0.
//
// v7: read/write TIME-SEPARATION. Evidence from 7 rounds: fill writes this
// buffer at 6.6 TB/s with NO reads; every gather variant (256B..4KB granule,
// NT or not, linear or plane-interleaved) sits at 2.4-3.7 TB/s -- and all of
// them mix demand reads (map/feat) into the write stream (HBM bus turnaround
// + controller fragmentation). v7: one block per CU owns 3348 consecutive
// cells; Phase A does ALL global reads (map slice once, occupied pillars'
// feat compacted into LDS, transposed); Phase B is a pure-write stream from
// LDS -- 13.4KB contiguous per channel per block, zero global reads.

#define C_CH   64
#define SLICE  3348       // n_map = 857088 = 256*3348; plane = 214272 = 64*3348
#define CAP    216        // pillar slots per block (lambda~157, +4.7 sigma)
#define BT     1024       // threads per block (16 waves)

typedef float fvec4 __attribute__((ext_vector_type(4)));

__global__ void build_map_kernel(const int* __restrict__ coords, int n_pillars,
                                 const int* __restrict__ nx_p,
                                 const int* __restrict__ ny_p,
                                 int* __restrict__ map) {
    int p = blockIdx.x * blockDim.x + threadIdx.x;
    if (p >= n_pillars) return;
    const int nx = nx_p[0];
    const int ny = ny_p[0];
    const int x = coords[3 * p + 0];
    const int y = coords[3 * p + 1];
    const int b = coords[3 * p + 2];
    const long long m = (long long)b * (long long)(nx * ny) + (long long)y * nx + x;
    map[m] = p;
}

__global__ __launch_bounds__(BT) void gather_slice_kernel(
    const float* __restrict__ feat, const int* __restrict__ map,
    const int* __restrict__ nx_p, const int* __restrict__ ny_p,
    float* __restrict__ out, int n_map) {
    // 55296 + 6712 + 864 + 4 = 62.9 KB static LDS
    __shared__ float featT[C_CH][CAP];                    // transposed feat slots
    __shared__ __align__(16) unsigned short slot_of[SLICE + 4];
    __shared__ int pil[CAP];
    __shared__ int cnt;

    const int T = threadIdx.x;
    if (T == 0) cnt = 0;
    __syncthreads();

    const int cell0 = blockIdx.x * SLICE;
    const int len = min(SLICE, n_map - cell0);
    const int plane = nx_p[0] * ny_p[0];   // uniform

    // ---- Phase A1: map slice -> slots (all global map reads happen here) ----
    for (int i = T; i < SLICE + 4; i += BT) {
        unsigned short s = 0xFFFFu;                      // empty
        if (i < len) {
            const int p = map[cell0 + i];
            if (p >= 0) {
                const int k = atomicAdd(&cnt, 1);
                if (k < CAP) { pil[k] = p; s = (unsigned short)k; }
                else s = 0xFFFEu;                        // overflow -> global path
            }
        }
        slot_of[i] = s;
    }
    __syncthreads();

    // ---- Phase A2: stage occupied pillars' feat into LDS (transposed) ----
    const int total = min(cnt, CAP);
    for (int idx = T; idx < total * C_CH; idx += BT) {
        const int s = idx >> 6;          // slot
        const int e = idx & 63;          // channel   (consecutive T -> coalesced)
        featT[e][s] = feat[(size_t)pil[s] * C_CH + e];
    }
    __syncthreads();

    // ---- Phase B: pure-write stream, no global reads ----
    const int b0 = cell0 / plane;
    const int bend = (cell0 + len - 1) / plane;
    const int local0 = cell0 - b0 * plane;
    const bool fast = (b0 == bend) && ((plane & 3) == 0) &&
                      ((local0 & 3) == 0) && ((len & 3) == 0);

    if (fast) {
        const int q = T;                 // quad id within slice
        const int nq = len >> 2;         // 837 quads
        if (q < nq) {
            const ushort4 sl = *reinterpret_cast<const ushort4*>(&slot_of[4 * q]);
            const unsigned short ss[4] = {sl.x, sl.y, sl.z, sl.w};
            fvec4* dst = (fvec4*)(out + (size_t)(b0 * C_CH) * (size_t)plane +
                                  local0 + 4 * q);
            const int pstep = plane >> 2;          // fvec4 stride per channel
#pragma unroll 4
            for (int c = 0; c < C_CH; ++c) {
                float vv[4];
#pragma unroll
                for (int j = 0; j < 4; ++j) {
                    const unsigned short s = ss[j];
                    float f = 0.0f;
                    if (s < CAP) f = featT[c][s];
                    else if (s == 0xFFFEu)          // overflow slot (rare/never)
                        f = feat[(size_t)map[cell0 + 4 * q + j] * C_CH + c];
                    vv[j] = f;
                }
                fvec4 v;
                v.x = vv[0]; v.y = vv[1]; v.z = vv[2]; v.w = vv[3];
                *dst = v;
                dst += pstep;
            }
        }
    } else {
        // Generic path: per-cell with batch-boundary guards (odd shapes only).
        for (int i = T; i < len; i += BT) {
            const int cell = cell0 + i;
            const int b = cell / plane;
            const int local = cell - b * plane;
            const int p = map[cell];
            for (int c = 0; c < C_CH; ++c) {
                out[((size_t)(b * C_CH + c)) * (size_t)plane + local] =
                    (p >= 0) ? feat[(size_t)p * C_CH + c] : 0.0f;
            }
        }
    }
}

// Fallback: direct scatter after zeroing the output (used only if ws is too
// small for the map or C != 64).
__global__ void direct_scatter_kernel(const float* __restrict__ feat,
                                      const int* __restrict__ coords,
                                      int n_pillars, int C,
                                      const int* __restrict__ nx_p,
                                      const int* __restrict__ ny_p,
                                      float* __restrict__ out) {
    const long long t = (long long)blockIdx.x * blockDim.x + threadIdx.x;
    if (t >= (long long)n_pillars * C) return;
    const int p = (int)(t / C);
    const int c = (int)(t - (long long)p * C);
    const int nx = nx_p[0];
    const int ny = ny_p[0];
    const int x = coords[3 * p + 0];
    const int y = coords[3 * p + 1];
    const int b = coords[3 * p + 2];
    const int plane = nx * ny;
    const size_t o = ((size_t)b * C + c) * (size_t)plane + (size_t)y * nx + x;
    out[o] = feat[(size_t)p * C + c];
}

extern "C" void kernel_launch(void* const* d_in, const int* in_sizes, int n_in,
                              void* d_out, int out_size, void* d_ws, size_t ws_size,
                              hipStream_t stream) {
    const float* feat   = (const float*)d_in[0];
    const int*   coords = (const int*)d_in[1];
    // d_in[2] = batch_size (device scalar, unused on host), d_in[3] = nx,
    // d_in[4] = ny — device-resident scalars, read inside the kernels.
    const int* nx_p = (const int*)d_in[3];
    const int* ny_p = (const int*)d_in[4];
    float* out = (float*)d_out;

    const int n_pillars = in_sizes[1] / 3;
    const int C = in_sizes[0] / n_pillars;
    const int n_map = out_size / C;                 // B * NY * NX
    const size_t map_bytes = (size_t)n_map * sizeof(int);

    if (C == C_CH && ws_size >= map_bytes) {
        int* map = (int*)d_ws;
        // 0xFF bytes -> every map entry == -1
        (void)hipMemsetAsync(map, 0xFF, map_bytes, stream);
        build_map_kernel<<<(n_pillars + 255) / 256, 256, 0, stream>>>(
            coords, n_pillars, nx_p, ny_p, map);

        const int n_blocks = (n_map + SLICE - 1) / SLICE;   // 256 for this shape
        gather_slice_kernel<<<n_blocks, BT, 0, stream>>>(
            feat, map, nx_p, ny_p, out, n_map);
    } else {
        (void)hipMemsetAsync(out, 0, (size_t)out_size * sizeof(float), stream);
        const long long total = (long long)n_pillars * C;
        direct_scatter_kernel<<<(unsigned)((total + 255) / 256), 256, 0, stream>>>(
            feat, coords, n_pillars, C, nx_p, ny_p, out);
    }
}